// Round 10
// baseline (406.047 us; speedup 1.0000x reference)
//
#include <hip/hip_runtime.h>
#include <math.h>

#define NNODES 40000
#define NEDGES 640000
#define NPB 8             // nodes per edge-block
#define CHUNK4 16         // edges per chunk in k_edge8
#define MROW 260          // mid row stride (floats): 16B-aligned, 4-bank row shift
#define NB1 8             // nodes per block, stage-1
#define NCPAD (157 * 256) // counts padded so scanABC int4 loads stay in-bounds

typedef __attribute__((ext_vector_type(8))) short short8_t;
typedef __attribute__((ext_vector_type(4))) short short4_t;
typedef __attribute__((ext_vector_type(4))) float float4_t;

__device__ __forceinline__ unsigned short bf16r(float x) {
  union { float f; unsigned u; } v; v.f = x;
  unsigned u = v.u;
  u += 0x7FFFu + ((u >> 16) & 1u);   // RNE
  return (unsigned short)(u >> 16);
}

#define INV_SQRT3_C 0.57735026918962576f

// ============ R12 (proven): stage-1 matmul + histogram fused =================
__global__ __launch_bounds__(256) void k1_hist(
    const float* __restrict__ node_input,
    const float* __restrict__ w1s,
    const float* __restrict__ w1v,
    float* __restrict__ A2,
    const int* __restrict__ edge_dst,
    int* __restrict__ counts) {
  __shared__ float rows[NB1 * 128];   // 4 KB
  __shared__ float ws[32 * 32];       // 4 KB (prescaled)
  __shared__ float wvv[32 * 32];      // 4 KB (prescaled)
  const float scale = 0.17677669529663687f; // 1/sqrt(32)
  int tid = threadIdx.x;
  int n0 = blockIdx.x * NB1;

  // hist share: first 2500 blocks cover 640000 edges, 256 each (coalesced read)
  int e = blockIdx.x * 256 + tid;
  if (e < NEDGES) atomicAdd(&counts[edge_dst[e]], 1);

  float4 a = ((const float4*)w1s)[tid];          // 256 float4 = full 32x32
  a.x *= scale; a.y *= scale; a.z *= scale; a.w *= scale;
  ((float4*)ws)[tid] = a;
  float4 b = ((const float4*)w1v)[tid];
  b.x *= scale; b.y *= scale; b.z *= scale; b.w *= scale;
  ((float4*)wvv)[tid] = b;
  ((float4*)rows)[tid] = ((const float4*)(node_input + (long)n0 * 128))[tid];
  __syncthreads();

  int j = tid & 31, g = tid >> 5;
  const float* lr = rows + g * 128;
  float ac0 = 0.f, ac1 = 0.f, ac2 = 0.f, ac3 = 0.f;
  #pragma unroll
  for (int t = 0; t < 32; ++t) {
    float wsj = ws[t * 32 + j];
    float wvj = wvv[t * 32 + j];
    ac0 = fmaf(lr[t],              wsj, ac0);
    ac1 = fmaf(lr[32 + 3 * t],     wvj, ac1);
    ac2 = fmaf(lr[32 + 3 * t + 1], wvj, ac2);
    ac3 = fmaf(lr[32 + 3 * t + 2], wvj, ac3);
  }
  float4 o; o.x = ac0; o.y = ac1; o.z = ac2; o.w = ac3;
  ((float4*)(A2 + (long)n0 * 128))[tid] = o;   // tid = g*32+j -> n0+g, u=j
}

// ============ R12 (proven): scanA+scanBC fused into ONE launch ===============
__global__ __launch_bounds__(256) void k_scanABC(
    const int* __restrict__ counts,
    int* __restrict__ offsets,
    int* __restrict__ cursor) {
  __shared__ int sb[256];
  __shared__ int s[256];
  int tid = threadIdx.x;
  int vb = 0;
  if (tid < 157) {
    const int4* c4 = (const int4*)(counts + tid * 256);
    #pragma unroll 8
    for (int i = 0; i < 64; ++i) {
      int4 v = c4[i];
      vb += v.x + v.y + v.z + v.w;
    }
  }
  sb[tid] = vb;
  __syncthreads();
  for (int d = 1; d < 256; d <<= 1) {
    int x = (tid >= d) ? sb[tid - d] : 0;
    __syncthreads();
    sb[tid] += x;
    __syncthreads();
  }
  int myboff = (blockIdx.x == 0) ? 0 : sb[blockIdx.x - 1];
  int t = blockIdx.x * 256 + tid;
  int v = (t < NNODES) ? counts[t] : 0;
  s[tid] = v;
  __syncthreads();
  for (int d = 1; d < 256; d <<= 1) {
    int x = (tid >= d) ? s[tid - d] : 0;
    __syncthreads();
    s[tid] += x;
    __syncthreads();
  }
  int off = myboff + s[tid] - v;
  if (t < NNODES) { offsets[t] = off; cursor[t] = off; }
  if (blockIdx.x == 0 && tid == 0) offsets[NNODES] = NEDGES;
}

// ============ tier1 scatter (R7, proven): one aligned 64B record per edge ====
__global__ void k_scatter_pack3(const int* __restrict__ edge_src,
                                const int* __restrict__ edge_dst,
                                const float* __restrict__ edge_attr,
                                const float* __restrict__ edge_scalars,
                                int* __restrict__ cursor,
                                float4_t* __restrict__ PE) {
  int e = blockIdx.x * blockDim.x + threadIdx.x;
  if (e < NEDGES) {
    int d = edge_dst[e];
    int p = atomicAdd(&cursor[d], 1);
    float4_t* b = PE + (long)p * 4;
    b[0] = *(const float4_t*)(edge_attr + (long)e * 4);
    b[1] = *(const float4_t*)(edge_scalars + (long)e * 8);
    b[2] = *(const float4_t*)(edge_scalars + (long)e * 8 + 4);
    float4_t sv;
    sv.x = __int_as_float(edge_src[e]); sv.y = 0.f; sv.z = 0.f; sv.w = 0.f;
    b[3] = sv;
  }
}

// ============ fused edge kernel — R13: occupancy unlock ======================
// R12 counters: MfmaUtil 3.4%, HBM 16%, VALU 52%, Occupancy 39% -- no pipe
// saturated => latency/barrier-bound, speed tracks resident waves (proven by
// the R9/R10 occupancy<->dur correlation). launch_bounds(256,4) was the cap:
// LDS 21.5KB allows 7 blocks/CU, VGPR 56 < 64 allows 8 waves/SIMD. Raise the
// residency target to 6 blocks/CU (24/32 waves). Sole change vs proven R12.
__global__ __launch_bounds__(256, 6) void k_edge8(
    const float* __restrict__ A2,
    const float4_t* __restrict__ PE,
    const float* __restrict__ fc_w1,
    const float* __restrict__ fc_w2,
    const float* __restrict__ w2s,
    const float* __restrict__ w2v,
    const int* __restrict__ offsets,
    float* __restrict__ out) {
  const float INV_SQRT8 = 0.35355339059327373f;
  const float H_SCALE   = 1.6791767923989418f / 8.0f; // SILU_NORM / sqrt(64)
  const float S2SCALE   = 0.03125f;                   // (1/sqrt(16))/sqrt(64)

  __shared__ float  mid[CHUNK4 * MROW];   // 16,640 B; reused as node rows at end
  __shared__ short  h_lds[CHUNK4 * 72];   //  2,304 B (144B row stride)
  __shared__ float4 w1f[144];             //  2,304 B

  int tid = threadIdx.x;
  int n0 = blockIdx.x * NPB;
  int ebase = offsets[n0];
  int eend  = offsets[n0 + NPB];

  if (tid < 128) {
    int j = tid >> 1, hf = tid & 1;
    float4 wv4;
    wv4.x = fc_w1[(hf * 4 + 0) * 64 + j] * INV_SQRT8;
    wv4.y = fc_w1[(hf * 4 + 1) * 64 + j] * INV_SQRT8;
    wv4.z = fc_w1[(hf * 4 + 2) * 64 + j] * INV_SQRT8;
    wv4.w = fc_w1[(hf * 4 + 3) * 64 + j] * INV_SQRT8;
    w1f[(j >> 3) * 18 + (j & 7) * 2 + hf] = wv4;
  }

  int wv = tid >> 6;       // wave id 0..3
  int l  = tid & 63;
  int m  = l & 15;
  int q  = l >> 4;
  int uh = wv & 1;         // u-half
  int cl = wv >> 1;        // column class
  int tL = cl * 2 + uh;
  int tH = 4 + cl * 2 + uh;
  int u  = uh * 16 + m;

  // B-frags direct from global (fc_w2 is 32KB, L2-resident)
  short8_t bL0, bL1, bH0, bH1;
  #pragma unroll
  for (int j = 0; j < 8; ++j) {
    bL0[j] = (short)bf16r(fc_w2[(q * 8 + j) * 128      + tL * 16 + m]);
    bL1[j] = (short)bf16r(fc_w2[(32 + q * 8 + j) * 128 + tL * 16 + m]);
    bH0[j] = (short)bf16r(fc_w2[(q * 8 + j) * 128      + tH * 16 + m]);
    bH1[j] = (short)bf16r(fc_w2[(32 + q * 8 + j) * 128 + tH * 16 + m]);
  }

  int nA = 2 * wv;
  int offA0 = offsets[n0 + nA];
  int offA1 = offsets[n0 + nA + 1];
  int offB1 = offsets[n0 + nA + 2];
  float4_t racA = {0.f, 0.f, 0.f, 0.f};
  float4_t racB = {0.f, 0.f, 0.f, 0.f};

  float ea0x, ea0y, ea0z, ea0w, ea1x, ea1y, ea1z, ea1w,
        ea2x, ea2y, ea2z, ea2w, ea3x, ea3y, ea3z, ea3w;
  float se0, se1, se2, se3, vx0, vx1, vx2, vx3,
        vy0, vy1, vy2, vy3, vz0, vz1, vz2, vz3;

  auto loadmeta = [&](int kb) {
    int ecs = kb + m;
    int ecc = (ecs < eend) ? ecs : (eend - 1);
    const float4_t* pb = PE + (long)ecc * 4;
    float4_t sA  = pb[1];
    float4_t sB  = pb[2];
    int g  = wv * 2 + (q >> 1);
    int ob = (q & 1) * 4;
    short4_t hq;
    #pragma unroll
    for (int j = 0; j < 4; ++j) {
      float4 wA = w1f[g * 18 + (ob + j) * 2 + 0];
      float4 wB = w1f[g * 18 + (ob + j) * 2 + 1];
      float x = sA.x * wA.x + sA.y * wA.y + sA.z * wA.z + sA.w * wA.w
              + sB.x * wB.x + sB.y * wB.y + sB.z * wB.z + sB.w * wB.w;
      float hv = (x * H_SCALE) * __builtin_amdgcn_rcpf(1.f + __expf(-x));
      hq[j] = (short)bf16r(hv);
    }
    *(short4_t*)((char*)h_lds + m * 144 + wv * 32 + q * 8) = hq;
    // EPI metadata: direct uniform PE loads (proven)
    int eb = kb + q * 4;
    int e0 = (eb     < eend) ? eb     : (eend - 1);
    int e1 = (eb + 1 < eend) ? eb + 1 : (eend - 1);
    int e2 = (eb + 2 < eend) ? eb + 2 : (eend - 1);
    int e3 = (eb + 3 < eend) ? eb + 3 : (eend - 1);
    const float4_t* p0 = PE + (long)e0 * 4;
    const float4_t* p1 = PE + (long)e1 * 4;
    const float4_t* p2 = PE + (long)e2 * 4;
    const float4_t* p3 = PE + (long)e3 * 4;
    float4_t a0v = p0[0]; int s0i = __float_as_int(p0[3].x);
    float4_t a1v = p1[0]; int s1i = __float_as_int(p1[3].x);
    float4_t a2v = p2[0]; int s2i = __float_as_int(p2[3].x);
    float4_t a3v = p3[0]; int s3i = __float_as_int(p3[3].x);
    ea0x = a0v.x; ea0y = a0v.y; ea0z = a0v.z; ea0w = a0v.w;
    ea1x = a1v.x; ea1y = a1v.y; ea1z = a1v.z; ea1w = a1v.w;
    ea2x = a2v.x; ea2y = a2v.y; ea2z = a2v.z; ea2w = a2v.w;
    ea3x = a3v.x; ea3y = a3v.y; ea3z = a3v.z; ea3w = a3v.w;
    float4 g0 = *(const float4*)(A2 + (long)s0i * 128 + 4 * u);
    float4 g1 = *(const float4*)(A2 + (long)s1i * 128 + 4 * u);
    float4 g2 = *(const float4*)(A2 + (long)s2i * 128 + 4 * u);
    float4 g3 = *(const float4*)(A2 + (long)s3i * 128 + 4 * u);
    se0 = g0.x; vx0 = g0.y; vy0 = g0.z; vz0 = g0.w;
    se1 = g1.x; vx1 = g1.y; vy1 = g1.z; vz1 = g1.w;
    se2 = g2.x; vx2 = g2.y; vy2 = g2.z; vz2 = g2.w;
    se3 = g3.x; vx3 = g3.y; vy3 = g3.z; vz3 = g3.w;
  };

  __syncthreads();    // w1f ready

  if (ebase < eend) {
    loadmeta(ebase);
    for (int k0 = ebase; k0 < eend; k0 += CHUNK4) {
      __syncthreads();  // h_lds published; prev-chunk mid reads done
      short8_t a0 = *(const short8_t*)((const char*)h_lds + m * 144 + q * 16);
      short8_t a1 = *(const short8_t*)((const char*)h_lds + m * 144 + 64 + q * 16);
      float4_t acL = {0.f, 0.f, 0.f, 0.f};
      float4_t acH = {0.f, 0.f, 0.f, 0.f};
      acL = __builtin_amdgcn_mfma_f32_16x16x32_bf16(a0, bL0, acL, 0, 0, 0);
      acL = __builtin_amdgcn_mfma_f32_16x16x32_bf16(a1, bL1, acL, 0, 0, 0);
      acH = __builtin_amdgcn_mfma_f32_16x16x32_bf16(a0, bH0, acH, 0, 0, 0);
      acH = __builtin_amdgcn_mfma_f32_16x16x32_bf16(a1, bH1, acH, 0, 0, 0);
#define EPI4(R, SE, VX, VY, VZ, EAX, EAY, EAZ, EAW) do {            \
        float* mrow = mid + (q * 4 + (R)) * MROW;                   \
        if (cl == 0) {                                              \
          mrow[u] = acL[R] * (SE) * (EAX);                          \
          float b = acH[R] * (EAX);                                 \
          mrow[160 + 3 * u + 0] = b * (VX);                         \
          mrow[160 + 3 * u + 1] = b * (VY);                         \
          mrow[160 + 3 * u + 2] = b * (VZ);                         \
        } else {                                                    \
          float dv = (VX) * (EAY) + (VY) * (EAZ) + (VZ) * (EAW);    \
          mrow[32 + u] = acH[R] * dv * INV_SQRT3_C;                 \
          float b = acL[R] * (SE);                                  \
          mrow[64 + 3 * u + 0] = b * (EAY);                         \
          mrow[64 + 3 * u + 1] = b * (EAZ);                         \
          mrow[64 + 3 * u + 2] = b * (EAW);                         \
        }                                                           \
      } while (0)
      EPI4(0, se0, vx0, vy0, vz0, ea0x, ea0y, ea0z, ea0w);
      EPI4(1, se1, vx1, vy1, vz1, ea1x, ea1y, ea1z, ea1w);
      EPI4(2, se2, vx2, vy2, vz2, ea2x, ea2y, ea2z, ea2w);
      EPI4(3, se3, vx3, vy3, vz3, ea3x, ea3y, ea3z, ea3w);
#undef EPI4
      __syncthreads();  // mid ready
      {
        int lo = (offA0 > k0) ? offA0 : k0;
        int hi = offA1 < (k0 + CHUNK4) ? offA1 : (k0 + CHUNK4);
        for (int e = lo; e < hi; ++e) {
          float4_t v = *(const float4_t*)(mid + (e - k0) * MROW + 4 * l);
          racA.x += v.x; racA.y += v.y; racA.z += v.z; racA.w += v.w;
        }
        int lo2 = (offA1 > k0) ? offA1 : k0;
        int hi2 = offB1 < (k0 + CHUNK4) ? offB1 : (k0 + CHUNK4);
        for (int e = lo2; e < hi2; ++e) {
          float4_t v = *(const float4_t*)(mid + (e - k0) * MROW + 4 * l);
          racB.x += v.x; racB.y += v.y; racB.z += v.z; racB.w += v.w;
        }
      }
      if (k0 + CHUNK4 < eend) loadmeta(k0 + CHUNK4);
    }
  }

  // ---- fused stage-2 epilogue (weights straight from L1/L2) ----
  __syncthreads();
  *(float4_t*)(mid + (2 * wv) * MROW + 4 * l)     = racA;
  *(float4_t*)(mid + (2 * wv + 1) * MROW + 4 * l) = racB;
  __syncthreads();
  {
    int j = tid & 31, g = tid >> 5;
    const float* nr = mid + g * MROW;
    float ac0 = 0.f, ac1 = 0.f, ac2 = 0.f, ac3 = 0.f;
    #pragma unroll 8
    for (int t = 0; t < 64; ++t) {
      float wsj = w2s[t * 32 + j];
      float wvj = w2v[t * 32 + j];
      ac0 = fmaf(nr[t],              wsj, ac0);
      ac1 = fmaf(nr[64 + 3 * t],     wvj, ac1);
      ac2 = fmaf(nr[64 + 3 * t + 1], wvj, ac2);
      ac3 = fmaf(nr[64 + 3 * t + 2], wvj, ac3);
    }
    float* po = out + (long)(n0 + g) * 128;
    po[j] = ac0 * S2SCALE;
    po[32 + 3 * j + 0] = ac1 * S2SCALE;
    po[32 + 3 * j + 1] = ac2 * S2SCALE;
    po[32 + 3 * j + 2] = ac3 * S2SCALE;
  }
}

extern "C" void kernel_launch(void* const* d_in, const int* in_sizes, int n_in,
                              void* d_out, int out_size, void* d_ws, size_t ws_size,
                              hipStream_t stream) {
  const float* node_input   = (const float*)d_in[0];
  const int*   edge_src     = (const int*)d_in[2];
  const int*   edge_dst     = (const int*)d_in[3];
  const float* edge_attr    = (const float*)d_in[4];
  const float* edge_scalars = (const float*)d_in[5];
  const float* w_lin1_s     = (const float*)d_in[6];
  const float* w_lin1_v     = (const float*)d_in[7];
  const float* fc_w1        = (const float*)d_in[8];
  const float* fc_w2        = (const float*)d_in[9];
  const float* w_lin2_s     = (const float*)d_in[10];
  const float* w_lin2_v     = (const float*)d_in[11];

  float* out = (float*)d_out;

  const size_t SZ_A2  = (size_t)NNODES * 128 * sizeof(float);   // 20.48 MB
  const size_t SZ_PE  = (size_t)NEDGES * 64;                    // 40.96 MB
  const size_t SZ_CNT = (size_t)NCPAD * sizeof(int);            // padded counts
  const size_t SZ_OFF = (size_t)(NNODES + 4) * sizeof(int);

  char* p = (char*)d_ws;
  float*    A2  = (float*)p;    p += SZ_A2;
  float4_t* PE  = (float4_t*)p; p += SZ_PE;
  int* counts   = (int*)p;      p += SZ_CNT;
  int* offsets  = (int*)p;      p += SZ_OFF;
  int* cursor   = (int*)p;      p += (size_t)NNODES * sizeof(int);

  // 5 graph nodes (proven R12 chain; only the edge kernel changed)
  hipMemsetAsync(counts, 0, SZ_CNT, stream);
  k1_hist<<<NNODES / NB1, 256, 0, stream>>>(node_input, w_lin1_s, w_lin1_v, A2,
                                            edge_dst, counts);
  k_scanABC<<<157, 256, 0, stream>>>(counts, offsets, cursor);
  k_scatter_pack3<<<NEDGES / 256, 256, 0, stream>>>(edge_src, edge_dst, edge_attr,
                                                    edge_scalars, cursor, PE);
  k_edge8<<<NNODES / NPB, 256, 0, stream>>>(A2, PE, fc_w1, fc_w2,
                                            w_lin2_s, w_lin2_v, offsets, out);
}

// Round 11
// 310.635 us; speedup vs baseline: 1.3071x; 1.3071x over previous
//
#include <hip/hip_runtime.h>
#include <math.h>

#define NNODES 40000
#define NEDGES 640000
#define NPB 8             // nodes per edge-block
#define CHUNK4 16         // edges per chunk in k_edge9
#define MROW 260          // mid row stride (floats): 16B-aligned, 4-bank row shift
#define NB1 8             // nodes per block, stage-1
#define NCPAD (157 * 256) // counts padded so scanABC int4 loads stay in-bounds

typedef __attribute__((ext_vector_type(8))) short short8_t;
typedef __attribute__((ext_vector_type(4))) short short4_t;
typedef __attribute__((ext_vector_type(4))) float float4_t;

__device__ __forceinline__ unsigned short bf16r(float x) {
  union { float f; unsigned u; } v; v.f = x;
  unsigned u = v.u;
  u += 0x7FFFu + ((u >> 16) & 1u);   // RNE
  return (unsigned short)(u >> 16);
}

#define INV_SQRT3_C 0.57735026918962576f

// ============ R12 (proven): stage-1 matmul + histogram fused =================
__global__ __launch_bounds__(256) void k1_hist(
    const float* __restrict__ node_input,
    const float* __restrict__ w1s,
    const float* __restrict__ w1v,
    float* __restrict__ A2,
    const int* __restrict__ edge_dst,
    int* __restrict__ counts) {
  __shared__ float rows[NB1 * 128];   // 4 KB
  __shared__ float ws[32 * 32];       // 4 KB (prescaled)
  __shared__ float wvv[32 * 32];      // 4 KB (prescaled)
  const float scale = 0.17677669529663687f; // 1/sqrt(32)
  int tid = threadIdx.x;
  int n0 = blockIdx.x * NB1;

  // hist share: first 2500 blocks cover 640000 edges, 256 each (coalesced read)
  int e = blockIdx.x * 256 + tid;
  if (e < NEDGES) atomicAdd(&counts[edge_dst[e]], 1);

  float4 a = ((const float4*)w1s)[tid];          // 256 float4 = full 32x32
  a.x *= scale; a.y *= scale; a.z *= scale; a.w *= scale;
  ((float4*)ws)[tid] = a;
  float4 b = ((const float4*)w1v)[tid];
  b.x *= scale; b.y *= scale; b.z *= scale; b.w *= scale;
  ((float4*)wvv)[tid] = b;
  ((float4*)rows)[tid] = ((const float4*)(node_input + (long)n0 * 128))[tid];
  __syncthreads();

  int j = tid & 31, g = tid >> 5;
  const float* lr = rows + g * 128;
  float ac0 = 0.f, ac1 = 0.f, ac2 = 0.f, ac3 = 0.f;
  #pragma unroll
  for (int t = 0; t < 32; ++t) {
    float wsj = ws[t * 32 + j];
    float wvj = wvv[t * 32 + j];
    ac0 = fmaf(lr[t],              wsj, ac0);
    ac1 = fmaf(lr[32 + 3 * t],     wvj, ac1);
    ac2 = fmaf(lr[32 + 3 * t + 1], wvj, ac2);
    ac3 = fmaf(lr[32 + 3 * t + 2], wvj, ac3);
  }
  float4 o; o.x = ac0; o.y = ac1; o.z = ac2; o.w = ac3;
  ((float4*)(A2 + (long)n0 * 128))[tid] = o;   // tid = g*32+j -> n0+g, u=j
}

// ============ R12 (proven): scanA+scanBC fused into ONE launch ===============
__global__ __launch_bounds__(256) void k_scanABC(
    const int* __restrict__ counts,
    int* __restrict__ offsets,
    int* __restrict__ cursor) {
  __shared__ int sb[256];
  __shared__ int s[256];
  int tid = threadIdx.x;
  int vb = 0;
  if (tid < 157) {
    const int4* c4 = (const int4*)(counts + tid * 256);
    #pragma unroll 8
    for (int i = 0; i < 64; ++i) {
      int4 v = c4[i];
      vb += v.x + v.y + v.z + v.w;
    }
  }
  sb[tid] = vb;
  __syncthreads();
  for (int d = 1; d < 256; d <<= 1) {
    int x = (tid >= d) ? sb[tid - d] : 0;
    __syncthreads();
    sb[tid] += x;
    __syncthreads();
  }
  int myboff = (blockIdx.x == 0) ? 0 : sb[blockIdx.x - 1];
  int t = blockIdx.x * 256 + tid;
  int v = (t < NNODES) ? counts[t] : 0;
  s[tid] = v;
  __syncthreads();
  for (int d = 1; d < 256; d <<= 1) {
    int x = (tid >= d) ? s[tid - d] : 0;
    __syncthreads();
    s[tid] += x;
    __syncthreads();
  }
  int off = myboff + s[tid] - v;
  if (t < NNODES) { offsets[t] = off; cursor[t] = off; }
  if (blockIdx.x == 0 && tid == 0) offsets[NNODES] = NEDGES;
}

// ============ tier1 scatter (R7, proven): one aligned 64B record per edge ====
__global__ void k_scatter_pack3(const int* __restrict__ edge_src,
                                const int* __restrict__ edge_dst,
                                const float* __restrict__ edge_attr,
                                const float* __restrict__ edge_scalars,
                                int* __restrict__ cursor,
                                float4_t* __restrict__ PE) {
  int e = blockIdx.x * blockDim.x + threadIdx.x;
  if (e < NEDGES) {
    int d = edge_dst[e];
    int p = atomicAdd(&cursor[d], 1);
    float4_t* b = PE + (long)p * 4;
    b[0] = *(const float4_t*)(edge_attr + (long)e * 4);
    b[1] = *(const float4_t*)(edge_scalars + (long)e * 8);
    b[2] = *(const float4_t*)(edge_scalars + (long)e * 8 + 4);
    float4_t sv;
    sv.x = __int_as_float(edge_src[e]); sv.y = 0.f; sv.z = 0.f; sv.w = 0.f;
    b[3] = sv;
  }
}

// ============ fused edge kernel — R14: clean occupancy test ==================
// R13 post-mortem: launch_bounds(256,6) forced VGPR 56->40 -> SCRATCH SPILLS
// (WRITE_SIZE 20->120MB, FETCH 156->413MB) -> 137->233us despite occupancy
// 39->58%. The occupancy hypothesis is still untested cleanly. (256,5) is the
// clean test: VGPR budget 512/5 ~= 102 >= 56 (no spill), LDS 5x21.5 = 107.5KB
// < 160KB (5 blocks/CU resident). Sole change vs the proven 137us R12 kernel.
// Expected: WRITE back to 20MB, VGPR ~56, occupancy ~48-50; dur 137 -> ~120 if
// latency-bound, ~137 if not (clean falsification either way).
__global__ __launch_bounds__(256, 5) void k_edge9(
    const float* __restrict__ A2,
    const float4_t* __restrict__ PE,
    const float* __restrict__ fc_w1,
    const float* __restrict__ fc_w2,
    const float* __restrict__ w2s,
    const float* __restrict__ w2v,
    const int* __restrict__ offsets,
    float* __restrict__ out) {
  const float INV_SQRT8 = 0.35355339059327373f;
  const float H_SCALE   = 1.6791767923989418f / 8.0f; // SILU_NORM / sqrt(64)
  const float S2SCALE   = 0.03125f;                   // (1/sqrt(16))/sqrt(64)

  __shared__ float  mid[CHUNK4 * MROW];   // 16,640 B; reused as node rows at end
  __shared__ short  h_lds[CHUNK4 * 72];   //  2,304 B (144B row stride)
  __shared__ float4 w1f[144];             //  2,304 B

  int tid = threadIdx.x;
  int n0 = blockIdx.x * NPB;
  int ebase = offsets[n0];
  int eend  = offsets[n0 + NPB];

  if (tid < 128) {
    int j = tid >> 1, hf = tid & 1;
    float4 wv4;
    wv4.x = fc_w1[(hf * 4 + 0) * 64 + j] * INV_SQRT8;
    wv4.y = fc_w1[(hf * 4 + 1) * 64 + j] * INV_SQRT8;
    wv4.z = fc_w1[(hf * 4 + 2) * 64 + j] * INV_SQRT8;
    wv4.w = fc_w1[(hf * 4 + 3) * 64 + j] * INV_SQRT8;
    w1f[(j >> 3) * 18 + (j & 7) * 2 + hf] = wv4;
  }

  int wv = tid >> 6;       // wave id 0..3
  int l  = tid & 63;
  int m  = l & 15;
  int q  = l >> 4;
  int uh = wv & 1;         // u-half
  int cl = wv >> 1;        // column class
  int tL = cl * 2 + uh;
  int tH = 4 + cl * 2 + uh;
  int u  = uh * 16 + m;

  // B-frags direct from global (fc_w2 is 32KB, L2-resident)
  short8_t bL0, bL1, bH0, bH1;
  #pragma unroll
  for (int j = 0; j < 8; ++j) {
    bL0[j] = (short)bf16r(fc_w2[(q * 8 + j) * 128      + tL * 16 + m]);
    bL1[j] = (short)bf16r(fc_w2[(32 + q * 8 + j) * 128 + tL * 16 + m]);
    bH0[j] = (short)bf16r(fc_w2[(q * 8 + j) * 128      + tH * 16 + m]);
    bH1[j] = (short)bf16r(fc_w2[(32 + q * 8 + j) * 128 + tH * 16 + m]);
  }

  int nA = 2 * wv;
  int offA0 = offsets[n0 + nA];
  int offA1 = offsets[n0 + nA + 1];
  int offB1 = offsets[n0 + nA + 2];
  float4_t racA = {0.f, 0.f, 0.f, 0.f};
  float4_t racB = {0.f, 0.f, 0.f, 0.f};

  float ea0x, ea0y, ea0z, ea0w, ea1x, ea1y, ea1z, ea1w,
        ea2x, ea2y, ea2z, ea2w, ea3x, ea3y, ea3z, ea3w;
  float se0, se1, se2, se3, vx0, vx1, vx2, vx3,
        vy0, vy1, vy2, vy3, vz0, vz1, vz2, vz3;

  auto loadmeta = [&](int kb) {
    int ecs = kb + m;
    int ecc = (ecs < eend) ? ecs : (eend - 1);
    const float4_t* pb = PE + (long)ecc * 4;
    float4_t sA  = pb[1];
    float4_t sB  = pb[2];
    int g  = wv * 2 + (q >> 1);
    int ob = (q & 1) * 4;
    short4_t hq;
    #pragma unroll
    for (int j = 0; j < 4; ++j) {
      float4 wA = w1f[g * 18 + (ob + j) * 2 + 0];
      float4 wB = w1f[g * 18 + (ob + j) * 2 + 1];
      float x = sA.x * wA.x + sA.y * wA.y + sA.z * wA.z + sA.w * wA.w
              + sB.x * wB.x + sB.y * wB.y + sB.z * wB.z + sB.w * wB.w;
      float hv = (x * H_SCALE) * __builtin_amdgcn_rcpf(1.f + __expf(-x));
      hq[j] = (short)bf16r(hv);
    }
    *(short4_t*)((char*)h_lds + m * 144 + wv * 32 + q * 8) = hq;
    // EPI metadata: direct uniform PE loads (proven)
    int eb = kb + q * 4;
    int e0 = (eb     < eend) ? eb     : (eend - 1);
    int e1 = (eb + 1 < eend) ? eb + 1 : (eend - 1);
    int e2 = (eb + 2 < eend) ? eb + 2 : (eend - 1);
    int e3 = (eb + 3 < eend) ? eb + 3 : (eend - 1);
    const float4_t* p0 = PE + (long)e0 * 4;
    const float4_t* p1 = PE + (long)e1 * 4;
    const float4_t* p2 = PE + (long)e2 * 4;
    const float4_t* p3 = PE + (long)e3 * 4;
    float4_t a0v = p0[0]; int s0i = __float_as_int(p0[3].x);
    float4_t a1v = p1[0]; int s1i = __float_as_int(p1[3].x);
    float4_t a2v = p2[0]; int s2i = __float_as_int(p2[3].x);
    float4_t a3v = p3[0]; int s3i = __float_as_int(p3[3].x);
    ea0x = a0v.x; ea0y = a0v.y; ea0z = a0v.z; ea0w = a0v.w;
    ea1x = a1v.x; ea1y = a1v.y; ea1z = a1v.z; ea1w = a1v.w;
    ea2x = a2v.x; ea2y = a2v.y; ea2z = a2v.z; ea2w = a2v.w;
    ea3x = a3v.x; ea3y = a3v.y; ea3z = a3v.z; ea3w = a3v.w;
    float4 g0 = *(const float4*)(A2 + (long)s0i * 128 + 4 * u);
    float4 g1 = *(const float4*)(A2 + (long)s1i * 128 + 4 * u);
    float4 g2 = *(const float4*)(A2 + (long)s2i * 128 + 4 * u);
    float4 g3 = *(const float4*)(A2 + (long)s3i * 128 + 4 * u);
    se0 = g0.x; vx0 = g0.y; vy0 = g0.z; vz0 = g0.w;
    se1 = g1.x; vx1 = g1.y; vy1 = g1.z; vz1 = g1.w;
    se2 = g2.x; vx2 = g2.y; vy2 = g2.z; vz2 = g2.w;
    se3 = g3.x; vx3 = g3.y; vy3 = g3.z; vz3 = g3.w;
  };

  __syncthreads();    // w1f ready

  if (ebase < eend) {
    loadmeta(ebase);
    for (int k0 = ebase; k0 < eend; k0 += CHUNK4) {
      __syncthreads();  // h_lds published; prev-chunk mid reads done
      short8_t a0 = *(const short8_t*)((const char*)h_lds + m * 144 + q * 16);
      short8_t a1 = *(const short8_t*)((const char*)h_lds + m * 144 + 64 + q * 16);
      float4_t acL = {0.f, 0.f, 0.f, 0.f};
      float4_t acH = {0.f, 0.f, 0.f, 0.f};
      acL = __builtin_amdgcn_mfma_f32_16x16x32_bf16(a0, bL0, acL, 0, 0, 0);
      acL = __builtin_amdgcn_mfma_f32_16x16x32_bf16(a1, bL1, acL, 0, 0, 0);
      acH = __builtin_amdgcn_mfma_f32_16x16x32_bf16(a0, bH0, acH, 0, 0, 0);
      acH = __builtin_amdgcn_mfma_f32_16x16x32_bf16(a1, bH1, acH, 0, 0, 0);
#define EPI4(R, SE, VX, VY, VZ, EAX, EAY, EAZ, EAW) do {            \
        float* mrow = mid + (q * 4 + (R)) * MROW;                   \
        if (cl == 0) {                                              \
          mrow[u] = acL[R] * (SE) * (EAX);                          \
          float b = acH[R] * (EAX);                                 \
          mrow[160 + 3 * u + 0] = b * (VX);                         \
          mrow[160 + 3 * u + 1] = b * (VY);                         \
          mrow[160 + 3 * u + 2] = b * (VZ);                         \
        } else {                                                    \
          float dv = (VX) * (EAY) + (VY) * (EAZ) + (VZ) * (EAW);    \
          mrow[32 + u] = acH[R] * dv * INV_SQRT3_C;                 \
          float b = acL[R] * (SE);                                  \
          mrow[64 + 3 * u + 0] = b * (EAY);                         \
          mrow[64 + 3 * u + 1] = b * (EAZ);                         \
          mrow[64 + 3 * u + 2] = b * (EAW);                         \
        }                                                           \
      } while (0)
      EPI4(0, se0, vx0, vy0, vz0, ea0x, ea0y, ea0z, ea0w);
      EPI4(1, se1, vx1, vy1, vz1, ea1x, ea1y, ea1z, ea1w);
      EPI4(2, se2, vx2, vy2, vz2, ea2x, ea2y, ea2z, ea2w);
      EPI4(3, se3, vx3, vy3, vz3, ea3x, ea3y, ea3z, ea3w);
#undef EPI4
      __syncthreads();  // mid ready
      {
        int lo = (offA0 > k0) ? offA0 : k0;
        int hi = offA1 < (k0 + CHUNK4) ? offA1 : (k0 + CHUNK4);
        for (int e = lo; e < hi; ++e) {
          float4_t v = *(const float4_t*)(mid + (e - k0) * MROW + 4 * l);
          racA.x += v.x; racA.y += v.y; racA.z += v.z; racA.w += v.w;
        }
        int lo2 = (offA1 > k0) ? offA1 : k0;
        int hi2 = offB1 < (k0 + CHUNK4) ? offB1 : (k0 + CHUNK4);
        for (int e = lo2; e < hi2; ++e) {
          float4_t v = *(const float4_t*)(mid + (e - k0) * MROW + 4 * l);
          racB.x += v.x; racB.y += v.y; racB.z += v.z; racB.w += v.w;
        }
      }
      if (k0 + CHUNK4 < eend) loadmeta(k0 + CHUNK4);
    }
  }

  // ---- fused stage-2 epilogue (weights straight from L1/L2) ----
  __syncthreads();
  *(float4_t*)(mid + (2 * wv) * MROW + 4 * l)     = racA;
  *(float4_t*)(mid + (2 * wv + 1) * MROW + 4 * l) = racB;
  __syncthreads();
  {
    int j = tid & 31, g = tid >> 5;
    const float* nr = mid + g * MROW;
    float ac0 = 0.f, ac1 = 0.f, ac2 = 0.f, ac3 = 0.f;
    #pragma unroll 8
    for (int t = 0; t < 64; ++t) {
      float wsj = w2s[t * 32 + j];
      float wvj = w2v[t * 32 + j];
      ac0 = fmaf(nr[t],              wsj, ac0);
      ac1 = fmaf(nr[64 + 3 * t],     wvj, ac1);
      ac2 = fmaf(nr[64 + 3 * t + 1], wvj, ac2);
      ac3 = fmaf(nr[64 + 3 * t + 2], wvj, ac3);
    }
    float* po = out + (long)(n0 + g) * 128;
    po[j] = ac0 * S2SCALE;
    po[32 + 3 * j + 0] = ac1 * S2SCALE;
    po[32 + 3 * j + 1] = ac2 * S2SCALE;
    po[32 + 3 * j + 2] = ac3 * S2SCALE;
  }
}

extern "C" void kernel_launch(void* const* d_in, const int* in_sizes, int n_in,
                              void* d_out, int out_size, void* d_ws, size_t ws_size,
                              hipStream_t stream) {
  const float* node_input   = (const float*)d_in[0];
  const int*   edge_src     = (const int*)d_in[2];
  const int*   edge_dst     = (const int*)d_in[3];
  const float* edge_attr    = (const float*)d_in[4];
  const float* edge_scalars = (const float*)d_in[5];
  const float* w_lin1_s     = (const float*)d_in[6];
  const float* w_lin1_v     = (const float*)d_in[7];
  const float* fc_w1        = (const float*)d_in[8];
  const float* fc_w2        = (const float*)d_in[9];
  const float* w_lin2_s     = (const float*)d_in[10];
  const float* w_lin2_v     = (const float*)d_in[11];

  float* out = (float*)d_out;

  const size_t SZ_A2  = (size_t)NNODES * 128 * sizeof(float);   // 20.48 MB
  const size_t SZ_PE  = (size_t)NEDGES * 64;                    // 40.96 MB
  const size_t SZ_CNT = (size_t)NCPAD * sizeof(int);            // padded counts
  const size_t SZ_OFF = (size_t)(NNODES + 4) * sizeof(int);

  char* p = (char*)d_ws;
  float*    A2  = (float*)p;    p += SZ_A2;
  float4_t* PE  = (float4_t*)p; p += SZ_PE;
  int* counts   = (int*)p;      p += SZ_CNT;
  int* offsets  = (int*)p;      p += SZ_OFF;
  int* cursor   = (int*)p;      p += (size_t)NNODES * sizeof(int);

  // 5 graph nodes (proven R12 chain; only the edge kernel's launch bound changed)
  hipMemsetAsync(counts, 0, SZ_CNT, stream);
  k1_hist<<<NNODES / NB1, 256, 0, stream>>>(node_input, w_lin1_s, w_lin1_v, A2,
                                            edge_dst, counts);
  k_scanABC<<<157, 256, 0, stream>>>(counts, offsets, cursor);
  k_scatter_pack3<<<NEDGES / 256, 256, 0, stream>>>(edge_src, edge_dst, edge_attr,
                                                    edge_scalars, cursor, PE);
  k_edge9<<<NNODES / NPB, 256, 0, stream>>>(A2, PE, fc_w1, fc_w2,
                                            w_lin2_s, w_lin2_v, offsets, out);
}